// Round 1
// baseline (5507.436 us; speedup 1.0000x reference)
//
#include <hip/hip_runtime.h>
#include <hip/hip_bf16.h>
#include <math.h>

// ---------------- problem constants ----------------
#define NTOP 20
#define ROI_DIM 50176   // 1024*7*7

// output offsets (floats, concatenated in reference return order)
#define O_BOXES  0          // 8*20*4      = 640
#define O_ENT    640        // 8*20*237    = 37920
#define O_REGC   38560      // 8*20*310    = 49600
#define O_POS    88160      // 8*20*2      = 320
#define O_REL    88480      // 8*20*20*10  = 32000
#define O_SCORES 120480     // 8*20        = 160
#define O_CLS    120640     // 8*238*64*64 = 7798784
#define O_REG    7919424    // 8*4*64*64   = 131072
#define O_CTR    8050496    // 8*1*64*64   = 32768

// ---------------- conv 3x3 + bias + BN + ReLU (fp32) ----------------
// block: 256 thr computes 64 oc x 64 x (one y row). grid (4, 64, 8)
__global__ __launch_bounds__(256) void conv3x3_bn_relu(
    const float* __restrict__ in, int Cin,
    const float* __restrict__ wgt, const float* __restrict__ cbias,
    const float* __restrict__ bng, const float* __restrict__ bnb,
    const float* __restrict__ bnm, const float* __restrict__ bnv,
    float* __restrict__ out)
{
  const int oc0 = blockIdx.x * 64;
  const int y   = blockIdx.y;
  const int b   = blockIdx.z;
  const int tid = threadIdx.x;
  const int tx  = tid & 15;   // x-group of 4 (x = tx*4..tx*4+3)
  const int ty  = tid >> 4;   // oc-group of 4

  __shared__ __align__(16) float sIn[8][3][68];  // [ch][row][x+1], stride 68 for 16B align
  __shared__ __align__(16) float sW[72][64];     // [ch*9+k][oc]

  float acc[4][4];
#pragma unroll
  for (int a = 0; a < 4; a++)
#pragma unroll
    for (int c = 0; c < 4; c++) acc[a][c] = 0.f;

  const float* inB = in + (size_t)b * Cin * 4096;

  for (int c0 = 0; c0 < Cin; c0 += 8) {
    __syncthreads();
    // stage input: 8 ch x 3 rows x 66 (x = -1..64)
    for (int e = tid; e < 8 * 3 * 66; e += 256) {
      int ch = e / 198;
      int rem = e - ch * 198;
      int rr = rem / 66;
      int xx = rem - rr * 66;
      int gy = y - 1 + rr;
      int gx = xx - 1;
      float v = 0.f;
      if ((unsigned)gy < 64u && (unsigned)gx < 64u)
        v = inB[(size_t)(c0 + ch) * 4096 + gy * 64 + gx];
      sIn[ch][rr][xx] = v;
    }
    // stage weights: 8 ch x 9 k x 64 oc, transposed so oc is contiguous
    {
      int oc = tid & 63;
      int gr = tid >> 6;  // 0..3, each loads 18 contiguous (c,k) elements
      const float* wp = wgt + ((size_t)(oc0 + oc) * Cin + c0) * 9 + gr * 18;
#pragma unroll
      for (int j = 0; j < 18; j++)
        sW[gr * 18 + j][oc] = wp[j];
    }
    __syncthreads();
#pragma unroll
    for (int ch = 0; ch < 8; ch++) {
      float vr[3][6];
#pragma unroll
      for (int rr = 0; rr < 3; rr++) {
        const float* rp = &sIn[ch][rr][tx * 4];
        float4 a4 = *(const float4*)rp;   // storage idx tx*4.. = global x-1..x+2
        vr[rr][0] = a4.x; vr[rr][1] = a4.y; vr[rr][2] = a4.z; vr[rr][3] = a4.w;
        vr[rr][4] = rp[4]; vr[rr][5] = rp[5];
      }
#pragma unroll
      for (int k = 0; k < 9; k++) {
        const int ky = k / 3, kx = k - (k / 3) * 3;
        float4 w4 = *(const float4*)&sW[ch * 9 + k][ty * 4];
#pragma unroll
        for (int j = 0; j < 4; j++) {
          float iv = vr[ky][kx + j];
          acc[0][j] = fmaf(w4.x, iv, acc[0][j]);
          acc[1][j] = fmaf(w4.y, iv, acc[1][j]);
          acc[2][j] = fmaf(w4.z, iv, acc[2][j]);
          acc[3][j] = fmaf(w4.w, iv, acc[3][j]);
        }
      }
    }
  }

#pragma unroll
  for (int oi = 0; oi < 4; oi++) {
    const int oc = oc0 + ty * 4 + oi;
    const float s  = bng[oc] / sqrtf(bnv[oc] + 1e-5f);
    const float t  = bnb[oc] - bnm[oc] * s;
    const float cb = cbias[oc];
    float4 o;
    o.x = fmaxf(fmaf(acc[oi][0] + cb, s, t), 0.f);
    o.y = fmaxf(fmaf(acc[oi][1] + cb, s, t), 0.f);
    o.z = fmaxf(fmaf(acc[oi][2] + cb, s, t), 0.f);
    o.w = fmaxf(fmaf(acc[oi][3] + cb, s, t), 0.f);
    *(float4*)&out[(((size_t)b * 256 + oc) * 64 + y) * 64 + tx * 4] = o;
  }
}

// ---------------- RPN 1x1 heads: cls(238)+reg(4)+ctr(1), fp32 ----------------
// grid 512 = (b,y); block 256 = 4 waves x 64 lanes(x)
__global__ __launch_bounds__(256) void rpn_head(
    const float* __restrict__ r,
    const float* __restrict__ cls_w, const float* __restrict__ cls_b,
    const float* __restrict__ reg_w, const float* __restrict__ reg_b,
    const float* __restrict__ ctr_w, const float* __restrict__ ctr_b,
    float* __restrict__ out_cls, float* __restrict__ out_reg,
    float* __restrict__ out_ctr)
{
  const int y = blockIdx.x & 63;
  const int b = blockIdx.x >> 6;
  const int tid = threadIdx.x;
  const int tx = tid & 63;
  const int ty = tid >> 6;

  __shared__ float rL[256][64];
  for (int c0 = 0; c0 < 256; c0 += 4)
    rL[c0 + ty][tx] = r[(((size_t)b * 256 + c0 + ty) * 64 + y) * 64 + tx];
  __syncthreads();

  const int start = ty * 61;
  const int end   = min(243, start + 61);
  for (int o = start; o < end; o += 4) {
    const float* wp[4];
    float acc[4] = {0.f, 0.f, 0.f, 0.f};
#pragma unroll
    for (int q = 0; q < 4; q++) {
      int oc = min(o + q, 242);
      wp[q] = (oc < 238) ? (cls_w + (size_t)oc * 256)
            : (oc < 242) ? (reg_w + (size_t)(oc - 238) * 256)
            : ctr_w;
    }
    for (int c = 0; c < 256; c++) {
      float rv = rL[c][tx];
      acc[0] = fmaf(wp[0][c], rv, acc[0]);
      acc[1] = fmaf(wp[1][c], rv, acc[1]);
      acc[2] = fmaf(wp[2][c], rv, acc[2]);
      acc[3] = fmaf(wp[3][c], rv, acc[3]);
    }
#pragma unroll
    for (int q = 0; q < 4; q++) {
      int oc = o + q;
      if (oc >= end) break;
      if (oc < 238)
        out_cls[(((size_t)b * 238 + oc) * 64 + y) * 64 + tx] = acc[q] + cls_b[oc];
      else if (oc < 242)
        out_reg[(((size_t)b * 4 + (oc - 238)) * 64 + y) * 64 + tx] = acc[q] + reg_b[oc - 238];
      else
        out_ctr[((size_t)b * 64 + y) * 64 + tx] = acc[q] + ctr_b[0];
    }
  }
}

// ---------------- top-k(20) + sigmoid boxes + integer ROI coords ----------------
__global__ __launch_bounds__(256) void topk_boxes_k(
    const float* __restrict__ out_ctr, const float* __restrict__ out_reg,
    float* __restrict__ out_boxes, float* __restrict__ out_scores,
    int* __restrict__ idxbuf, int* __restrict__ pixbuf)
{
  const int b = blockIdx.x;
  const int tid = threadIdx.x;
  __shared__ float vals[4096];
  __shared__ float rv[256];
  __shared__ int   ri[256];
  for (int i = tid; i < 4096; i += 256) vals[i] = out_ctr[(size_t)b * 4096 + i];
  __syncthreads();
  for (int n = 0; n < NTOP; n++) {
    float best = -INFINITY;
    int bi = 1 << 30;
    for (int i = tid; i < 4096; i += 256) {
      float v = vals[i];
      if (v > best) { best = v; bi = i; }   // ascending i: keeps lowest index on ties
    }
    rv[tid] = best; ri[tid] = bi;
    __syncthreads();
    for (int s = 128; s > 0; s >>= 1) {
      if (tid < s) {
        float ov = rv[tid + s]; int oi = ri[tid + s];
        if (ov > rv[tid] || (ov == rv[tid] && oi < ri[tid])) { rv[tid] = ov; ri[tid] = oi; }
      }
      __syncthreads();
    }
    if (tid == 0) {
      const int idx = ri[0];
      const float val = rv[0];
      vals[idx] = -INFINITY;
      idxbuf[b * NTOP + n] = idx;
      out_scores[b * NTOP + n] = 1.f / (1.f + expf(-val));
      float bx[4];
#pragma unroll
      for (int j = 0; j < 4; j++) {
        float s0 = out_reg[((size_t)b * 4 + j) * 4096 + idx];
        bx[j] = 1.f / (1.f + expf(-s0));
        out_boxes[((size_t)b * NTOP + n) * 4 + j] = bx[j];
      }
      int x1 = min(63, max(0, (int)floorf(bx[0] * 64.f)));
      int y1 = min(63, max(0, (int)floorf(bx[1] * 64.f)));
      int x2 = max(x1 + 1, min((int)floorf(bx[2] * 64.f) + 1, 64));
      int y2 = max(y1 + 1, min((int)floorf(bx[3] * 64.f) + 1, 64));
      pixbuf[(b * NTOP + n) * 4 + 0] = x1;
      pixbuf[(b * NTOP + n) * 4 + 1] = y1;
      pixbuf[(b * NTOP + n) * 4 + 2] = x2;
      pixbuf[(b * NTOP + n) * 4 + 3] = y2;
    }
    __syncthreads();
  }
}

// ---------------- ROI pooling (direct region mean over vf) ----------------
// grid 160 = (b,n); block 256 over channels. roi[bn][c*49 + py*7 + px]
__global__ __launch_bounds__(256) void roi_pool_k(
    const float* __restrict__ vf, const int* __restrict__ pixbuf,
    float* __restrict__ roi)
{
  const int bn = blockIdx.x;
  const int b = bn / NTOP;
  const int tid = threadIdx.x;
  const int x1 = pixbuf[bn * 4 + 0], y1 = pixbuf[bn * 4 + 1];
  const int x2 = pixbuf[bn * 4 + 2], y2 = pixbuf[bn * 4 + 3];
  const int iw = x2 - x1, ih = y2 - y1;
  int xs[7], xe[7], ys[7], ye[7];
#pragma unroll
  for (int i = 0; i < 7; i++) {
    xs[i] = x1 + (i * iw) / 7;
    xe[i] = x1 + ((i + 1) * iw + 6) / 7;   // ceil — cells may overlap by design (matches ref)
    ys[i] = y1 + (i * ih) / 7;
    ye[i] = y1 + ((i + 1) * ih + 6) / 7;
  }
  for (int c = tid; c < 1024; c += 256) {
    const float* base = vf + ((size_t)b * 1024 + c) * 4096;
    float* rp = roi + (size_t)bn * ROI_DIM + c * 49;
    for (int py = 0; py < 7; py++) {
      for (int px = 0; px < 7; px++) {
        float acc = 0.f;
        for (int yy = ys[py]; yy < ye[py]; yy++) {
          const float* row = base + yy * 64;
          for (int xx = xs[px]; xx < xe[px]; xx++) acc += row[xx];
        }
        float area = (float)((ye[py] - ys[py]) * (xe[px] - xs[px]));
        rp[py * 7 + px] = acc / area;
      }
    }
  }
}

// ---------------- zero fill ----------------
__global__ void zero_k(float* __restrict__ p, int n)
{
  int i = blockIdx.x * 256 + threadIdx.x;
  if (i < n) p[i] = 0.f;
}

#define FMA16(a4, b4, acc) \
  acc[0][0] = fmaf(a4.x, b4.x, acc[0][0]); acc[0][1] = fmaf(a4.x, b4.y, acc[0][1]); \
  acc[0][2] = fmaf(a4.x, b4.z, acc[0][2]); acc[0][3] = fmaf(a4.x, b4.w, acc[0][3]); \
  acc[1][0] = fmaf(a4.y, b4.x, acc[1][0]); acc[1][1] = fmaf(a4.y, b4.y, acc[1][1]); \
  acc[1][2] = fmaf(a4.y, b4.z, acc[1][2]); acc[1][3] = fmaf(a4.y, b4.w, acc[1][3]); \
  acc[2][0] = fmaf(a4.z, b4.x, acc[2][0]); acc[2][1] = fmaf(a4.z, b4.y, acc[2][1]); \
  acc[2][2] = fmaf(a4.z, b4.z, acc[2][2]); acc[2][3] = fmaf(a4.z, b4.w, acc[2][3]); \
  acc[3][0] = fmaf(a4.w, b4.x, acc[3][0]); acc[3][1] = fmaf(a4.w, b4.y, acc[3][1]); \
  acc[3][2] = fmaf(a4.w, b4.z, acc[3][2]); acc[3][3] = fmaf(a4.w, b4.w, acc[3][3]);

// ---------------- roi(160x50176) @ [ent|regc|pos|obj]_w1 -> H(160x2560), split-K atomic ----------------
// grid (ksplit=16, ntile=20, mtile=5); MT=32 NT=128 KT=32
__global__ __launch_bounds__(256) void mlp1_gemm_k(
    const float* __restrict__ A,
    const float* __restrict__ w_ent, const float* __restrict__ w_regc,
    const float* __restrict__ w_pos, const float* __restrict__ w_obj,
    float* __restrict__ Hbuf)
{
  const int ks = blockIdx.x;
  const int nt = blockIdx.y;
  const int mt = blockIdx.z;
  const float* Bp; int ldb, bn0;
  if (nt < 6)       { Bp = w_ent;  ldb = 768; bn0 = nt * 128; }
  else if (nt < 12) { Bp = w_regc; ldb = 768; bn0 = (nt - 6) * 128; }
  else if (nt < 14) { Bp = w_pos;  ldb = 256; bn0 = (nt - 12) * 128; }
  else              { Bp = w_obj;  ldb = 768; bn0 = (nt - 14) * 128; }
  const int m0 = mt * 32;
  const int tid = threadIdx.x;
  const int tn = tid & 31, tm = tid >> 5;
  __shared__ __align__(16) float As[32][32];
  __shared__ __align__(16) float Bs[32][128];
  float acc[4][4];
#pragma unroll
  for (int a = 0; a < 4; a++)
#pragma unroll
    for (int c = 0; c < 4; c++) acc[a][c] = 0.f;

  const int kbeg = ks * 3136, kend = kbeg + 3136;
  const int am = tid >> 3, ak = (tid & 7) * 4;
  for (int k0 = kbeg; k0 < kend; k0 += 32) {
    __syncthreads();
    {
      float4 a4 = *(const float4*)&A[(size_t)(m0 + am) * ROI_DIM + k0 + ak];
      As[ak + 0][am] = a4.x; As[ak + 1][am] = a4.y;
      As[ak + 2][am] = a4.z; As[ak + 3][am] = a4.w;
    }
#pragma unroll
    for (int p = 0; p < 4; p++) {
      int kk = (tid >> 5) + p * 8;
      int nn = (tid & 31) * 4;
      *(float4*)&Bs[kk][nn] = *(const float4*)&Bp[(size_t)(k0 + kk) * ldb + bn0 + nn];
    }
    __syncthreads();
#pragma unroll
    for (int kk = 0; kk < 32; kk++) {
      float4 a4 = *(const float4*)&As[kk][tm * 4];
      float4 b4 = *(const float4*)&Bs[kk][tn * 4];
      FMA16(a4, b4, acc)
    }
  }
  const int gn0 = nt * 128 + tn * 4;
#pragma unroll
  for (int i = 0; i < 4; i++) {
    float* hp = &Hbuf[(size_t)(m0 + tm * 4 + i) * 2560 + gn0];
    atomicAdd(hp + 0, acc[i][0]);
    atomicAdd(hp + 1, acc[i][1]);
    atomicAdd(hp + 2, acc[i][2]);
    atomicAdd(hp + 3, acc[i][3]);
  }
}

// ---------------- bias + ReLU (obj section: bias only) ----------------
__global__ void mlp1_epilogue_k(float* __restrict__ Hbuf,
    const float* __restrict__ b_ent, const float* __restrict__ b_regc,
    const float* __restrict__ b_pos, const float* __restrict__ b_obj)
{
  int idx = blockIdx.x * 256 + threadIdx.x;
  if (idx >= 160 * 2560) return;
  int n = idx % 2560;
  float h = Hbuf[idx];
  if (n < 768)       { h += b_ent[n];        h = fmaxf(h, 0.f); }
  else if (n < 1536) { h += b_regc[n - 768]; h = fmaxf(h, 0.f); }
  else if (n < 1792) { h += b_pos[n - 1536]; h = fmaxf(h, 0.f); }
  else               { h += b_obj[n - 1792]; }
  Hbuf[idx] = h;
}

// ---------------- generic second-layer head: out = H @ W2 + b2 ----------------
__global__ void head2_k(
    const float* __restrict__ Hsrc, int ldh, int hoff,
    const float* __restrict__ W2, const float* __restrict__ b2,
    int K, int Nn, int M, float* __restrict__ outp)
{
  int idx = blockIdx.x * 256 + threadIdx.x;
  if (idx >= M * Nn) return;
  int m = idx / Nn;
  int n = idx - m * Nn;
  const float* h = Hsrc + (size_t)m * ldh + hoff;
  float acc = b2[n];
  for (int k = 0; k < K; k++) acc = fmaf(h[k], W2[(size_t)k * Nn + n], acc);
  outp[idx] = acc;
}

// ---------------- spatial MLP on box pairs ----------------
__global__ void sp_hidden_k(const float* __restrict__ boxes,
    const float* __restrict__ w1, const float* __restrict__ b1,
    float* __restrict__ sph)
{
  int idx = blockIdx.x * 256 + threadIdx.x;  // 3200*64
  if (idx >= 3200 * 64) return;
  int pp = idx >> 6, hh = idx & 63;
  int b = pp / 400;
  int rem = pp - b * 400;
  int i = rem / 20, j = rem - (rem / 20) * 20;
  const float* bi = boxes + ((size_t)b * NTOP + i) * 4;
  const float* bj = boxes + ((size_t)b * NTOP + j) * 4;
  float acc = b1[hh];
#pragma unroll
  for (int k = 0; k < 4; k++) acc = fmaf(bi[k], w1[k * 64 + hh], acc);
#pragma unroll
  for (int k = 0; k < 4; k++) acc = fmaf(bj[k], w1[(k + 4) * 64 + hh], acc);
  sph[idx] = fmaxf(acc, 0.f);
}

__global__ void sp_out_k(const float* __restrict__ sph,
    const float* __restrict__ w2, const float* __restrict__ b2,
    float* __restrict__ spbuf)
{
  int idx = blockIdx.x * 256 + threadIdx.x;  // 3200*192
  if (idx >= 3200 * 192) return;
  int pp = idx / 192, oc = idx - pp * 192;
  const float* hp = sph + (size_t)pp * 64;
  float acc = b2[oc];
  for (int h = 0; h < 64; h++) acc = fmaf(hp[h], w2[h * 192 + oc], acc);
  spbuf[idx] = acc;
}

// ---------------- rel layer-1 GEMM: gathered concat(subj,obj,sp)(3200x1728) @ rel_w1 -> relh ----------------
// grid (ntile=6, mtile=100); fused bias+ReLU (segment boundaries 768/1536 are 32-aligned)
__global__ __launch_bounds__(256) void rel_gemm_k(
    const float* __restrict__ Hbuf, const float* __restrict__ spbuf,
    const float* __restrict__ Bw, const float* __restrict__ bias,
    float* __restrict__ relh)
{
  const int nt = blockIdx.x;
  const int mt = blockIdx.y;
  const int m0 = mt * 32;
  const int tid = threadIdx.x;
  const int tn = tid & 31, tm = tid >> 5;
  __shared__ __align__(16) float As[32][32];
  __shared__ __align__(16) float Bs[32][128];
  float acc[4][4];
#pragma unroll
  for (int a = 0; a < 4; a++)
#pragma unroll
    for (int c = 0; c < 4; c++) acc[a][c] = 0.f;

  const int am = tid >> 3, ak = (tid & 7) * 4;
  const int p = m0 + am;
  const int b = p / 400;
  const int rem = p - b * 400;
  const int ii = rem / 20;
  const int jj = rem - ii * 20;
  const float* obj_i = Hbuf + (size_t)(b * NTOP + ii) * 2560 + 1792;
  const float* obj_j = Hbuf + (size_t)(b * NTOP + jj) * 2560 + 1792;
  const float* spp   = spbuf + (size_t)p * 192;
  const int bn0 = nt * 128;

  for (int k0 = 0; k0 < 1728; k0 += 32) {
    __syncthreads();
    {
      int k = k0 + ak;
      float4 a4;
      if (k < 768)       a4 = *(const float4*)&obj_i[k];
      else if (k < 1536) a4 = *(const float4*)&obj_j[k - 768];
      else               a4 = *(const float4*)&spp[k - 1536];
      As[ak + 0][am] = a4.x; As[ak + 1][am] = a4.y;
      As[ak + 2][am] = a4.z; As[ak + 3][am] = a4.w;
    }
#pragma unroll
    for (int q = 0; q < 4; q++) {
      int kk = (tid >> 5) + q * 8;
      int nn = (tid & 31) * 4;
      *(float4*)&Bs[kk][nn] = *(const float4*)&Bw[(size_t)(k0 + kk) * 768 + bn0 + nn];
    }
    __syncthreads();
#pragma unroll
    for (int kk = 0; kk < 32; kk++) {
      float4 a4 = *(const float4*)&As[kk][tm * 4];
      float4 b4 = *(const float4*)&Bs[kk][tn * 4];
      FMA16(a4, b4, acc)
    }
  }
  const int gn0 = bn0 + tn * 4;
#pragma unroll
  for (int i = 0; i < 4; i++) {
    int m = m0 + tm * 4 + i;
    float4 o;
    o.x = fmaxf(acc[i][0] + bias[gn0 + 0], 0.f);
    o.y = fmaxf(acc[i][1] + bias[gn0 + 1], 0.f);
    o.z = fmaxf(acc[i][2] + bias[gn0 + 2], 0.f);
    o.w = fmaxf(acc[i][3] + bias[gn0 + 3], 0.f);
    *(float4*)&relh[(size_t)m * 768 + gn0] = o;
  }
}

// ---------------- launch ----------------
extern "C" void kernel_launch(void* const* d_in, const int* in_sizes, int n_in,
                              void* d_out, int out_size, void* d_ws, size_t ws_size,
                              hipStream_t stream)
{
  const float* vf      = (const float*)d_in[0];
  const float* conv1_w = (const float*)d_in[1];
  const float* conv1_b = (const float*)d_in[2];
  const float* bn1_g   = (const float*)d_in[3];
  const float* bn1_b   = (const float*)d_in[4];
  const float* bn1_m   = (const float*)d_in[5];
  const float* bn1_v   = (const float*)d_in[6];
  const float* conv2_w = (const float*)d_in[7];
  const float* conv2_b = (const float*)d_in[8];
  const float* bn2_g   = (const float*)d_in[9];
  const float* bn2_b   = (const float*)d_in[10];
  const float* bn2_m   = (const float*)d_in[11];
  const float* bn2_v   = (const float*)d_in[12];
  const float* cls_w   = (const float*)d_in[13];
  const float* cls_b   = (const float*)d_in[14];
  const float* reg_w   = (const float*)d_in[15];
  const float* reg_b   = (const float*)d_in[16];
  const float* ctr_w   = (const float*)d_in[17];
  const float* ctr_b   = (const float*)d_in[18];
  const float* ent_w1  = (const float*)d_in[19];
  const float* ent_b1  = (const float*)d_in[20];
  const float* ent_w2  = (const float*)d_in[21];
  const float* ent_b2  = (const float*)d_in[22];
  const float* regc_w1 = (const float*)d_in[23];
  const float* regc_b1 = (const float*)d_in[24];
  const float* regc_w2 = (const float*)d_in[25];
  const float* regc_b2 = (const float*)d_in[26];
  const float* pos_w1  = (const float*)d_in[27];
  const float* pos_b1  = (const float*)d_in[28];
  const float* pos_w2  = (const float*)d_in[29];
  const float* pos_b2  = (const float*)d_in[30];
  const float* objp_w  = (const float*)d_in[31];
  const float* objp_b  = (const float*)d_in[32];
  const float* rel_w1  = (const float*)d_in[33];
  const float* rel_b1  = (const float*)d_in[34];
  const float* rel_w2  = (const float*)d_in[35];
  const float* rel_b2  = (const float*)d_in[36];
  const float* sp_w1   = (const float*)d_in[37];
  const float* sp_b1   = (const float*)d_in[38];
  const float* sp_w2   = (const float*)d_in[39];
  const float* sp_b2   = (const float*)d_in[40];

  float* out = (float*)d_out;
  float* o_boxes  = out + O_BOXES;
  float* o_ent    = out + O_ENT;
  float* o_regc   = out + O_REGC;
  float* o_pos    = out + O_POS;
  float* o_rel    = out + O_REL;
  float* o_scores = out + O_SCORES;
  float* o_cls    = out + O_CLS;
  float* o_reg    = out + O_REG;
  float* o_ctr    = out + O_CTR;

  float* ws = (float*)d_ws;
  float* r1    = ws;                      // 8,388,608 floats
  float* r2    = ws + 8388608;            // 8,388,608
  float* roi   = r1;                      // alias: r1 dead after conv2
  float* Hbuf  = ws + 16777216;           // 409,600
  float* relh  = ws + 17186816;           // 2,457,600
  float* sph   = ws + 19644416;           // 204,800
  float* spbuf = ws + 19849216;           // 614,400
  int*   idxb  = (int*)(ws + 20463616);   // 160
  int*   pixb  = (int*)(ws + 20463776);   // 640   (total ws: ~82 MB)

  conv3x3_bn_relu<<<dim3(4, 64, 8), 256, 0, stream>>>(
      vf, 1024, conv1_w, conv1_b, bn1_g, bn1_b, bn1_m, bn1_v, r1);
  conv3x3_bn_relu<<<dim3(4, 64, 8), 256, 0, stream>>>(
      r1, 256, conv2_w, conv2_b, bn2_g, bn2_b, bn2_m, bn2_v, r2);
  rpn_head<<<512, 256, 0, stream>>>(
      r2, cls_w, cls_b, reg_w, reg_b, ctr_w, ctr_b, o_cls, o_reg, o_ctr);
  topk_boxes_k<<<8, 256, 0, stream>>>(o_ctr, o_reg, o_boxes, o_scores, idxb, pixb);
  roi_pool_k<<<160, 256, 0, stream>>>(vf, pixb, roi);
  zero_k<<<1600, 256, 0, stream>>>(Hbuf, 160 * 2560);
  mlp1_gemm_k<<<dim3(16, 20, 5), 256, 0, stream>>>(
      roi, ent_w1, regc_w1, pos_w1, objp_w, Hbuf);
  mlp1_epilogue_k<<<1600, 256, 0, stream>>>(Hbuf, ent_b1, regc_b1, pos_b1, objp_b);
  head2_k<<<(160 * 237 + 255) / 256, 256, 0, stream>>>(
      Hbuf, 2560, 0, ent_w2, ent_b2, 768, 237, 160, o_ent);
  head2_k<<<(160 * 310 + 255) / 256, 256, 0, stream>>>(
      Hbuf, 2560, 768, regc_w2, regc_b2, 768, 310, 160, o_regc);
  head2_k<<<(160 * 2 + 255) / 256, 256, 0, stream>>>(
      Hbuf, 2560, 1536, pos_w2, pos_b2, 256, 2, 160, o_pos);
  sp_hidden_k<<<800, 256, 0, stream>>>(o_boxes, sp_w1, sp_b1, sph);
  sp_out_k<<<2400, 256, 0, stream>>>(sph, sp_w2, sp_b2, spbuf);
  rel_gemm_k<<<dim3(6, 100), 256, 0, stream>>>(Hbuf, spbuf, rel_w1, rel_b1, relh);
  head2_k<<<(3200 * 10 + 255) / 256, 256, 0, stream>>>(
      relh, 768, 0, rel_w2, rel_b2, 768, 10, 3200, o_rel);
}

// Round 2
// 2844.279 us; speedup vs baseline: 1.9363x; 1.9363x over previous
//
#include <hip/hip_runtime.h>
#include <hip/hip_bf16.h>
#include <math.h>

// ---------------- problem constants ----------------
#define NTOP 20
#define ROI_DIM 50176   // 1024*7*7

// output offsets (floats, concatenated in reference return order)
#define O_BOXES  0
#define O_ENT    640
#define O_REGC   38560
#define O_POS    88160
#define O_REL    88480
#define O_SCORES 120480
#define O_CLS    120640
#define O_REG    7919424
#define O_CTR    8050496

typedef unsigned short u16;
typedef unsigned int   u32;
typedef short s8v __attribute__((ext_vector_type(8)));   // 8 bf16 operand frag
typedef float f4v __attribute__((ext_vector_type(4)));   // 4 f32 acc frag

__device__ inline u16 f2bf(float x) {
  union { float f; u32 u; } v; v.f = x;
  u32 r = (v.u + 0x7FFFu + ((v.u >> 16) & 1u)) >> 16;
  return (u16)r;
}
__device__ inline float bf2f(u16 h) {
  union { u32 u; float f; } v; v.u = ((u32)h) << 16;
  return v.f;
}

// ---------------- weight transform: OIHW fp32 -> [phase][oc][ci] bf16 hi/lo ----------------
__global__ void wt_transform_k(const float* __restrict__ w, int Cin,
                               u16* __restrict__ wh, u16* __restrict__ wl)
{
  int t = blockIdx.x * 256 + threadIdx.x;
  int total = 9 * 256 * Cin;
  if (t >= total) return;
  int ci = t % Cin;
  int rest = t / Cin;
  int oc = rest % 256;
  int ph = rest / 256;
  float v = w[((size_t)oc * Cin + ci) * 9 + ph];
  u16 h = f2bf(v);
  u16 l = f2bf(v - bf2f(h));
  wh[t] = h; wl[t] = l;
}

// ---------------- MFMA conv 3x3 pad1, split-bf16 (3-product ~fp32 accuracy) ----------------
// GEMM view: D[oc][px] = sum_{ci,ky,kx} W[oc][ci,ky,kx] * In[ci][y+ky-1][x+kx-1]
// grid (2 mtiles of 128 oc, 256 ntiles of 128 px = 2 rows of one image), block 256 = 4 waves
// wave tile 64oc x 64px as 4x4 of 16x16x32 mfma; 3 mfma per product (HH, LH, HL)
// MODE 0: conv1 (in: vf fp32 NCHW Cin=1024; out: NHWC bf16 hi/lo)
// MODE 1: conv2 (in: NHWC bf16 hi/lo Cin=256; out: fp32 NCHW)
template<int MODE>
__global__ __launch_bounds__(256) void conv_mfma_k(
    const float* __restrict__ vf,
    const u16* __restrict__ inH, const u16* __restrict__ inL,
    const u16* __restrict__ wH, const u16* __restrict__ wL,
    const float* __restrict__ cbias,
    const float* __restrict__ bng, const float* __restrict__ bnb,
    const float* __restrict__ bnm, const float* __restrict__ bnv,
    u16* __restrict__ outH, u16* __restrict__ outL,
    float* __restrict__ outF)
{
  const int Cin = (MODE == 0) ? 1024 : 256;
  const int mt = blockIdx.x;
  const int nt = blockIdx.y;
  const int b  = nt >> 5;
  const int y0 = (nt & 31) * 2;
  const int tid  = threadIdx.x;
  const int wave = tid >> 6;
  const int lane = tid & 63;
  const int lid  = lane & 15;
  const int quad = lane >> 4;
  const int wm = wave & 1;   // oc half (64)
  const int wn = wave >> 1;  // px half (64)

  // x-slot stride 40 u16 = 80B: 16B-aligned vectors, bank pattern 2 lanes/bank (free)
  __shared__ __align__(16) u16 sInH[4 * 66 * 40];
  __shared__ __align__(16) u16 sInL[4 * 66 * 40];
  __shared__ __align__(16) u16 sAH[128 * 40];
  __shared__ __align__(16) u16 sAL[128 * 40];

  f4v acc[4][4];
#pragma unroll
  for (int i = 0; i < 4; i++)
#pragma unroll
    for (int j = 0; j < 4; j++) { acc[i][j][0] = 0.f; acc[i][j][1] = 0.f; acc[i][j][2] = 0.f; acc[i][j][3] = 0.f; }

  for (int ci0 = 0; ci0 < Cin; ci0 += 32) {
    __syncthreads();
    if (MODE == 0) {
      // stage from fp32 NCHW: unit = (row,slot,cipair); lanes sweep ci-pairs -> conflict-free LDS
      for (int e = tid; e < 4224; e += 256) {
        int cip = e & 15;
        int sl  = (e >> 4) % 66;
        int row = (e >> 4) / 66;
        int gy = y0 - 1 + row, gx = sl - 1;
        float v0 = 0.f, v1 = 0.f;
        if ((unsigned)gy < 64u && (unsigned)gx < 64u) {
          const float* p = vf + ((size_t)(b * 1024 + ci0 + cip * 2) * 64 + gy) * 64 + gx;
          v0 = p[0]; v1 = p[4096];
        }
        u16 h0 = f2bf(v0); u16 l0 = f2bf(v0 - bf2f(h0));
        u16 h1 = f2bf(v1); u16 l1 = f2bf(v1 - bf2f(h1));
        int o = (row * 66 + sl) * 40 + cip * 2;
        *(u32*)&sInH[o] = (u32)h0 | ((u32)h1 << 16);
        *(u32*)&sInL[o] = (u32)l0 | ((u32)l1 << 16);
      }
    } else {
      // stage from NHWC bf16 hi/lo: 16B vector loads + 16B LDS writes
      for (int e = tid; e < 1056; e += 256) {
        int sub = e & 3;
        int sl  = (e >> 2) % 66;
        int row = (e >> 2) / 66;
        int gy = y0 - 1 + row, gx = sl - 1;
        uint4 vh = make_uint4(0, 0, 0, 0), vl = make_uint4(0, 0, 0, 0);
        if ((unsigned)gy < 64u && (unsigned)gx < 64u) {
          size_t gi = (size_t)((b * 64 + gy) * 64 + gx) * 256 + ci0 + sub * 8;
          vh = *(const uint4*)&inH[gi];
          vl = *(const uint4*)&inL[gi];
        }
        int o = (row * 66 + sl) * 40 + sub * 8;
        *(uint4*)&sInH[o] = vh;
        *(uint4*)&sInL[o] = vl;
      }
    }
    for (int ph = 0; ph < 9; ph++) {
      __syncthreads();
      // stage A: 128 oc x 32 ci (hi+lo), from [phase][oc][ci]
      for (int e = tid; e < 512; e += 256) {
        int oc = e >> 2, sub = e & 3;
        size_t gi = (size_t)(ph * 256 + mt * 128 + oc) * Cin + ci0 + sub * 8;
        int o = oc * 40 + sub * 8;
        *(uint4*)&sAH[o] = *(const uint4*)&wH[gi];
        *(uint4*)&sAL[o] = *(const uint4*)&wL[gi];
      }
      __syncthreads();
      const int ky = ph / 3, kx = ph - ky * 3;
      s8v BH[4], BL[4];
#pragma unroll
      for (int ni = 0; ni < 4; ni++) {
        int px = wn * 64 + ni * 16 + lid;
        int o = (((px >> 6) + ky) * 66 + (px & 63) + kx) * 40 + quad * 8;
        BH[ni] = *(s8v*)&sInH[o];
        BL[ni] = *(s8v*)&sInL[o];
      }
#pragma unroll
      for (int mi = 0; mi < 4; mi++) {
        int o = (wm * 64 + mi * 16 + lid) * 40 + quad * 8;
        s8v AH = *(s8v*)&sAH[o];
        s8v AL = *(s8v*)&sAL[o];
#pragma unroll
        for (int ni = 0; ni < 4; ni++) {
          acc[mi][ni] = __builtin_amdgcn_mfma_f32_16x16x32_bf16(AH, BH[ni], acc[mi][ni], 0, 0, 0);
          acc[mi][ni] = __builtin_amdgcn_mfma_f32_16x16x32_bf16(AL, BH[ni], acc[mi][ni], 0, 0, 0);
          acc[mi][ni] = __builtin_amdgcn_mfma_f32_16x16x32_bf16(AH, BL[ni], acc[mi][ni], 0, 0, 0);
        }
      }
    }
  }

  // epilogue: bias + BN + ReLU; C/D layout col=lane&15, row=quad*4+r (m89-verified)
#pragma unroll
  for (int mi = 0; mi < 4; mi++) {
#pragma unroll
    for (int ni = 0; ni < 4; ni++) {
      int px = wn * 64 + ni * 16 + lid;
      int gy = y0 + (px >> 6), gx = px & 63;
      if (MODE == 0) {
        u16 hs[4], ls[4];
#pragma unroll
        for (int r = 0; r < 4; r++) {
          int oc = mt * 128 + wm * 64 + mi * 16 + quad * 4 + r;
          float s = bng[oc] / sqrtf(bnv[oc] + 1e-5f);
          float t = bnb[oc] - bnm[oc] * s;
          float val = fmaxf(fmaf(acc[mi][ni][r] + cbias[oc], s, t), 0.f);
          hs[r] = f2bf(val);
          ls[r] = f2bf(val - bf2f(hs[r]));
        }
        size_t base = (size_t)((b * 64 + gy) * 64 + gx) * 256 + mt * 128 + wm * 64 + mi * 16 + quad * 4;
        uint2 hp, lp;
        hp.x = (u32)hs[0] | ((u32)hs[1] << 16); hp.y = (u32)hs[2] | ((u32)hs[3] << 16);
        lp.x = (u32)ls[0] | ((u32)ls[1] << 16); lp.y = (u32)ls[2] | ((u32)ls[3] << 16);
        *(uint2*)&outH[base] = hp;
        *(uint2*)&outL[base] = lp;
      } else {
#pragma unroll
        for (int r = 0; r < 4; r++) {
          int oc = mt * 128 + wm * 64 + mi * 16 + quad * 4 + r;
          float s = bng[oc] / sqrtf(bnv[oc] + 1e-5f);
          float t = bnb[oc] - bnm[oc] * s;
          float val = fmaxf(fmaf(acc[mi][ni][r] + cbias[oc], s, t), 0.f);
          outF[((size_t)(b * 256 + oc) * 64 + gy) * 64 + gx] = val;
        }
      }
    }
  }
}

// ---------------- RPN 1x1 heads: cls(238)+reg(4)+ctr(1), fp32 ----------------
__global__ __launch_bounds__(256) void rpn_head(
    const float* __restrict__ r,
    const float* __restrict__ cls_w, const float* __restrict__ cls_b,
    const float* __restrict__ reg_w, const float* __restrict__ reg_b,
    const float* __restrict__ ctr_w, const float* __restrict__ ctr_b,
    float* __restrict__ out_cls, float* __restrict__ out_reg,
    float* __restrict__ out_ctr)
{
  const int y = blockIdx.x & 63;
  const int b = blockIdx.x >> 6;
  const int tid = threadIdx.x;
  const int tx = tid & 63;
  const int ty = tid >> 6;

  __shared__ float rL[256][64];
  for (int c0 = 0; c0 < 256; c0 += 4)
    rL[c0 + ty][tx] = r[(((size_t)b * 256 + c0 + ty) * 64 + y) * 64 + tx];
  __syncthreads();

  const int start = ty * 61;
  const int end   = min(243, start + 61);
  for (int o = start; o < end; o += 4) {
    const float* wp[4];
    float acc[4] = {0.f, 0.f, 0.f, 0.f};
#pragma unroll
    for (int q = 0; q < 4; q++) {
      int oc = min(o + q, 242);
      wp[q] = (oc < 238) ? (cls_w + (size_t)oc * 256)
            : (oc < 242) ? (reg_w + (size_t)(oc - 238) * 256)
            : ctr_w;
    }
    for (int c = 0; c < 256; c++) {
      float rv = rL[c][tx];
      acc[0] = fmaf(wp[0][c], rv, acc[0]);
      acc[1] = fmaf(wp[1][c], rv, acc[1]);
      acc[2] = fmaf(wp[2][c], rv, acc[2]);
      acc[3] = fmaf(wp[3][c], rv, acc[3]);
    }
#pragma unroll
    for (int q = 0; q < 4; q++) {
      int oc = o + q;
      if (oc >= end) break;
      if (oc < 238)
        out_cls[(((size_t)b * 238 + oc) * 64 + y) * 64 + tx] = acc[q] + cls_b[oc];
      else if (oc < 242)
        out_reg[(((size_t)b * 4 + (oc - 238)) * 64 + y) * 64 + tx] = acc[q] + reg_b[oc - 238];
      else
        out_ctr[((size_t)b * 64 + y) * 64 + tx] = acc[q] + ctr_b[0];
    }
  }
}

// ---------------- top-k(20) + sigmoid boxes + integer ROI coords ----------------
__global__ __launch_bounds__(256) void topk_boxes_k(
    const float* __restrict__ out_ctr, const float* __restrict__ out_reg,
    float* __restrict__ out_boxes, float* __restrict__ out_scores,
    int* __restrict__ idxbuf, int* __restrict__ pixbuf)
{
  const int b = blockIdx.x;
  const int tid = threadIdx.x;
  __shared__ float vals[4096];
  __shared__ float rv[256];
  __shared__ int   ri[256];
  for (int i = tid; i < 4096; i += 256) vals[i] = out_ctr[(size_t)b * 4096 + i];
  __syncthreads();
  for (int n = 0; n < NTOP; n++) {
    float best = -INFINITY;
    int bi = 1 << 30;
    for (int i = tid; i < 4096; i += 256) {
      float v = vals[i];
      if (v > best) { best = v; bi = i; }
    }
    rv[tid] = best; ri[tid] = bi;
    __syncthreads();
    for (int s = 128; s > 0; s >>= 1) {
      if (tid < s) {
        float ov = rv[tid + s]; int oi = ri[tid + s];
        if (ov > rv[tid] || (ov == rv[tid] && oi < ri[tid])) { rv[tid] = ov; ri[tid] = oi; }
      }
      __syncthreads();
    }
    if (tid == 0) {
      const int idx = ri[0];
      const float val = rv[0];
      vals[idx] = -INFINITY;
      idxbuf[b * NTOP + n] = idx;
      out_scores[b * NTOP + n] = 1.f / (1.f + expf(-val));
      float bx[4];
#pragma unroll
      for (int j = 0; j < 4; j++) {
        float s0 = out_reg[((size_t)b * 4 + j) * 4096 + idx];
        bx[j] = 1.f / (1.f + expf(-s0));
        out_boxes[((size_t)b * NTOP + n) * 4 + j] = bx[j];
      }
      int x1 = min(63, max(0, (int)floorf(bx[0] * 64.f)));
      int y1 = min(63, max(0, (int)floorf(bx[1] * 64.f)));
      int x2 = max(x1 + 1, min((int)floorf(bx[2] * 64.f) + 1, 64));
      int y2 = max(y1 + 1, min((int)floorf(bx[3] * 64.f) + 1, 64));
      pixbuf[(b * NTOP + n) * 4 + 0] = x1;
      pixbuf[(b * NTOP + n) * 4 + 1] = y1;
      pixbuf[(b * NTOP + n) * 4 + 2] = x2;
      pixbuf[(b * NTOP + n) * 4 + 3] = y2;
    }
    __syncthreads();
  }
}

// ---------------- ROI pooling (direct region mean over vf) -> bf16 ----------------
__global__ __launch_bounds__(256) void roi_pool_k(
    const float* __restrict__ vf, const int* __restrict__ pixbuf,
    u16* __restrict__ roi)
{
  const int bn = blockIdx.x;
  const int b = bn / NTOP;
  const int tid = threadIdx.x;
  const int x1 = pixbuf[bn * 4 + 0], y1 = pixbuf[bn * 4 + 1];
  const int x2 = pixbuf[bn * 4 + 2], y2 = pixbuf[bn * 4 + 3];
  const int iw = x2 - x1, ih = y2 - y1;
  int xs[7], xe[7], ys[7], ye[7];
#pragma unroll
  for (int i = 0; i < 7; i++) {
    xs[i] = x1 + (i * iw) / 7;
    xe[i] = x1 + ((i + 1) * iw + 6) / 7;
    ys[i] = y1 + (i * ih) / 7;
    ye[i] = y1 + ((i + 1) * ih + 6) / 7;
  }
  for (int c = tid; c < 1024; c += 256) {
    const float* base = vf + ((size_t)b * 1024 + c) * 4096;
    u16* rp = roi + (size_t)bn * ROI_DIM + c * 49;
    for (int py = 0; py < 7; py++) {
      for (int px = 0; px < 7; px++) {
        float acc = 0.f;
        for (int yy = ys[py]; yy < ye[py]; yy++) {
          const float* row = base + yy * 64;
          for (int xx = xs[px]; xx < xe[px]; xx++) acc += row[xx];
        }
        float area = (float)((ye[py] - ys[py]) * (xe[px] - xs[px]));
        rp[py * 7 + px] = f2bf(acc / area);
      }
    }
  }
}

// ---------------- zero fill ----------------
__global__ void zero_k(float* __restrict__ p, int n)
{
  int i = blockIdx.x * 256 + threadIdx.x;
  if (i < n) p[i] = 0.f;
}

// ---------------- mlp1: roiB(160x50176 bf16) @ [ent|regc|pos|obj]_w1 -> Hbuf(160x2560), MFMA + split-K ----------------
// grid (nb=40 fastest for L2 A-reuse, ks=16); block tile M=160 N=64 Kchunk=3136
__global__ __launch_bounds__(256) void mlp1_mfma_k(
    const u16* __restrict__ A,
    const float* __restrict__ w_ent, const float* __restrict__ w_regc,
    const float* __restrict__ w_pos, const float* __restrict__ w_obj,
    float* __restrict__ Hbuf)
{
  const int nb = blockIdx.x;
  const int ks = blockIdx.y;
  const float* Bp; int ldw, col0;
  if (nb < 12)      { Bp = w_ent;  ldw = 768; col0 = nb * 64; }
  else if (nb < 24) { Bp = w_regc; ldw = 768; col0 = (nb - 12) * 64; }
  else if (nb < 28) { Bp = w_pos;  ldw = 256; col0 = (nb - 24) * 64; }
  else              { Bp = w_obj;  ldw = 768; col0 = (nb - 28) * 64; }
  const int tid  = threadIdx.x;
  const int wave = tid >> 6;
  const int lane = tid & 63;
  const int lid  = lane & 15;
  const int quad = lane >> 4;

  __shared__ __align__(16) u16 sA[160 * 72];  // ldk 72 u16 (pad): conflict-free frag reads
  __shared__ __align__(16) u16 sB[64 * 72];

  f4v acc[10];
#pragma unroll
  for (int i = 0; i < 10; i++) { acc[i][0] = 0.f; acc[i][1] = 0.f; acc[i][2] = 0.f; acc[i][3] = 0.f; }

  const int kbeg = ks * 3136;
  for (int k0 = kbeg; k0 < kbeg + 3136; k0 += 64) {
    __syncthreads();
    for (int e = tid; e < 1280; e += 256) {
      int m = e >> 3, sub = e & 7;
      *(uint4*)&sA[m * 72 + sub * 8] = *(const uint4*)&A[(size_t)m * 50176 + k0 + sub * 8];
    }
    for (int e = tid; e < 4096; e += 256) {
      int k = e >> 6, n = e & 63;
      sB[n * 72 + k] = f2bf(Bp[(size_t)(k0 + k) * ldw + col0 + n]);
    }
    __syncthreads();
#pragma unroll
    for (int ksub = 0; ksub < 2; ksub++) {
      s8v Bf = *(s8v*)&sB[(wave * 16 + lid) * 72 + ksub * 32 + quad * 8];
#pragma unroll
      for (int mf = 0; mf < 10; mf++) {
        s8v Af = *(s8v*)&sA[(mf * 16 + lid) * 72 + ksub * 32 + quad * 8];
        acc[mf] = __builtin_amdgcn_mfma_f32_16x16x32_bf16(Af, Bf, acc[mf], 0, 0, 0);
      }
    }
  }
  const int n = nb * 64 + wave * 16 + lid;
#pragma unroll
  for (int mf = 0; mf < 10; mf++)
#pragma unroll
    for (int r = 0; r < 4; r++) {
      int m = mf * 16 + quad * 4 + r;
      atomicAdd(&Hbuf[(size_t)m * 2560 + n], acc[mf][r]);
    }
}

// ---------------- bias + ReLU (obj section: bias only) ----------------
__global__ void mlp1_epilogue_k(float* __restrict__ Hbuf,
    const float* __restrict__ b_ent, const float* __restrict__ b_regc,
    const float* __restrict__ b_pos, const float* __restrict__ b_obj)
{
  int idx = blockIdx.x * 256 + threadIdx.x;
  if (idx >= 160 * 2560) return;
  int n = idx % 2560;
  float h = Hbuf[idx];
  if (n < 768)       { h += b_ent[n];        h = fmaxf(h, 0.f); }
  else if (n < 1536) { h += b_regc[n - 768]; h = fmaxf(h, 0.f); }
  else if (n < 1792) { h += b_pos[n - 1536]; h = fmaxf(h, 0.f); }
  else               { h += b_obj[n - 1792]; }
  Hbuf[idx] = h;
}

// ---------------- generic second-layer head: out = H @ W2 + b2 ----------------
__global__ void head2_k(
    const float* __restrict__ Hsrc, int ldh, int hoff,
    const float* __restrict__ W2, const float* __restrict__ b2,
    int K, int Nn, int M, float* __restrict__ outp)
{
  int idx = blockIdx.x * 256 + threadIdx.x;
  if (idx >= M * Nn) return;
  int m = idx / Nn;
  int n = idx - m * Nn;
  const float* h = Hsrc + (size_t)m * ldh + hoff;
  float acc = b2[n];
  for (int k = 0; k < K; k++) acc = fmaf(h[k], W2[(size_t)k * Nn + n], acc);
  outp[idx] = acc;
}

// ---------------- spatial MLP on box pairs ----------------
__global__ void sp_hidden_k(const float* __restrict__ boxes,
    const float* __restrict__ w1, const float* __restrict__ b1,
    float* __restrict__ sph)
{
  int idx = blockIdx.x * 256 + threadIdx.x;
  if (idx >= 3200 * 64) return;
  int pp = idx >> 6, hh = idx & 63;
  int b = pp / 400;
  int rem = pp - b * 400;
  int i = rem / 20, j = rem - (rem / 20) * 20;
  const float* bi = boxes + ((size_t)b * NTOP + i) * 4;
  const float* bj = boxes + ((size_t)b * NTOP + j) * 4;
  float acc = b1[hh];
#pragma unroll
  for (int k = 0; k < 4; k++) acc = fmaf(bi[k], w1[k * 64 + hh], acc);
#pragma unroll
  for (int k = 0; k < 4; k++) acc = fmaf(bj[k], w1[(k + 4) * 64 + hh], acc);
  sph[idx] = fmaxf(acc, 0.f);
}

__global__ void sp_out_k(const float* __restrict__ sph,
    const float* __restrict__ w2, const float* __restrict__ b2,
    float* __restrict__ spbuf)
{
  int idx = blockIdx.x * 256 + threadIdx.x;
  if (idx >= 3200 * 192) return;
  int pp = idx / 192, oc = idx - pp * 192;
  const float* hp = sph + (size_t)pp * 64;
  float acc = b2[oc];
  for (int h = 0; h < 64; h++) acc = fmaf(hp[h], w2[h * 192 + oc], acc);
  spbuf[idx] = acc;
}

#define FMA16(a4, b4, acc) \
  acc[0][0] = fmaf(a4.x, b4.x, acc[0][0]); acc[0][1] = fmaf(a4.x, b4.y, acc[0][1]); \
  acc[0][2] = fmaf(a4.x, b4.z, acc[0][2]); acc[0][3] = fmaf(a4.x, b4.w, acc[0][3]); \
  acc[1][0] = fmaf(a4.y, b4.x, acc[1][0]); acc[1][1] = fmaf(a4.y, b4.y, acc[1][1]); \
  acc[1][2] = fmaf(a4.y, b4.z, acc[1][2]); acc[1][3] = fmaf(a4.y, b4.w, acc[1][3]); \
  acc[2][0] = fmaf(a4.z, b4.x, acc[2][0]); acc[2][1] = fmaf(a4.z, b4.y, acc[2][1]); \
  acc[2][2] = fmaf(a4.z, b4.z, acc[2][2]); acc[2][3] = fmaf(a4.z, b4.w, acc[2][3]); \
  acc[3][0] = fmaf(a4.w, b4.x, acc[3][0]); acc[3][1] = fmaf(a4.w, b4.y, acc[3][1]); \
  acc[3][2] = fmaf(a4.w, b4.z, acc[3][2]); acc[3][3] = fmaf(a4.w, b4.w, acc[3][3]);

// ---------------- rel layer-1 GEMM (fp32) ----------------
__global__ __launch_bounds__(256) void rel_gemm_k(
    const float* __restrict__ Hbuf, const float* __restrict__ spbuf,
    const float* __restrict__ Bw, const float* __restrict__ bias,
    float* __restrict__ relh)
{
  const int nt = blockIdx.x;
  const int mt = blockIdx.y;
  const int m0 = mt * 32;
  const int tid = threadIdx.x;
  const int tn = tid & 31, tm = tid >> 5;
  __shared__ __align__(16) float As[32][32];
  __shared__ __align__(16) float Bs[32][128];
  float acc[4][4];
#pragma unroll
  for (int a = 0; a < 4; a++)
#pragma unroll
    for (int c = 0; c < 4; c++) acc[a][c] = 0.f;

  const int am = tid >> 3, ak = (tid & 7) * 4;
  const int p = m0 + am;
  const int b = p / 400;
  const int rem = p - b * 400;
  const int ii = rem / 20;
  const int jj = rem - ii * 20;
  const float* obj_i = Hbuf + (size_t)(b * NTOP + ii) * 2560 + 1792;
  const float* obj_j = Hbuf + (size_t)(b * NTOP + jj) * 2560 + 1792;
  const float* spp   = spbuf + (size_t)p * 192;
  const int bn0 = nt * 128;

  for (int k0 = 0; k0 < 1728; k0 += 32) {
    __syncthreads();
    {
      int k = k0 + ak;
      float4 a4;
      if (k < 768)       a4 = *(const float4*)&obj_i[k];
      else if (k < 1536) a4 = *(const float4*)&obj_j[k - 768];
      else               a4 = *(const float4*)&spp[k - 1536];
      As[ak + 0][am] = a4.x; As[ak + 1][am] = a4.y;
      As[ak + 2][am] = a4.z; As[ak + 3][am] = a4.w;
    }
#pragma unroll
    for (int q = 0; q < 4; q++) {
      int kk = (tid >> 5) + q * 8;
      int nn = (tid & 31) * 4;
      *(float4*)&Bs[kk][nn] = *(const float4*)&Bw[(size_t)(k0 + kk) * 768 + bn0 + nn];
    }
    __syncthreads();
#pragma unroll
    for (int kk = 0; kk < 32; kk++) {
      float4 a4 = *(const float4*)&As[kk][tm * 4];
      float4 b4 = *(const float4*)&Bs[kk][tn * 4];
      FMA16(a4, b4, acc)
    }
  }
  const int gn0 = bn0 + tn * 4;
#pragma unroll
  for (int i = 0; i < 4; i++) {
    int m = m0 + tm * 4 + i;
    float4 o;
    o.x = fmaxf(acc[i][0] + bias[gn0 + 0], 0.f);
    o.y = fmaxf(acc[i][1] + bias[gn0 + 1], 0.f);
    o.z = fmaxf(acc[i][2] + bias[gn0 + 2], 0.f);
    o.w = fmaxf(acc[i][3] + bias[gn0 + 3], 0.f);
    *(float4*)&relh[(size_t)m * 768 + gn0] = o;
  }
}

// ---------------- launch ----------------
extern "C" void kernel_launch(void* const* d_in, const int* in_sizes, int n_in,
                              void* d_out, int out_size, void* d_ws, size_t ws_size,
                              hipStream_t stream)
{
  const float* vf      = (const float*)d_in[0];
  const float* conv1_w = (const float*)d_in[1];
  const float* conv1_b = (const float*)d_in[2];
  const float* bn1_g   = (const float*)d_in[3];
  const float* bn1_b   = (const float*)d_in[4];
  const float* bn1_m   = (const float*)d_in[5];
  const float* bn1_v   = (const float*)d_in[6];
  const float* conv2_w = (const float*)d_in[7];
  const float* conv2_b = (const float*)d_in[8];
  const float* bn2_g   = (const float*)d_in[9];
  const float* bn2_b   = (const float*)d_in[10];
  const float* bn2_m   = (const float*)d_in[11];
  const float* bn2_v   = (const float*)d_in[12];
  const float* cls_w   = (const float*)d_in[13];
  const float* cls_b   = (const float*)d_in[14];
  const float* reg_w   = (const float*)d_in[15];
  const float* reg_b   = (const float*)d_in[16];
  const float* ctr_w   = (const float*)d_in[17];
  const float* ctr_b   = (const float*)d_in[18];
  const float* ent_w1  = (const float*)d_in[19];
  const float* ent_b1  = (const float*)d_in[20];
  const float* ent_w2  = (const float*)d_in[21];
  const float* ent_b2  = (const float*)d_in[22];
  const float* regc_w1 = (const float*)d_in[23];
  const float* regc_b1 = (const float*)d_in[24];
  const float* regc_w2 = (const float*)d_in[25];
  const float* regc_b2 = (const float*)d_in[26];
  const float* pos_w1  = (const float*)d_in[27];
  const float* pos_b1  = (const float*)d_in[28];
  const float* pos_w2  = (const float*)d_in[29];
  const float* pos_b2  = (const float*)d_in[30];
  const float* objp_w  = (const float*)d_in[31];
  const float* objp_b  = (const float*)d_in[32];
  const float* rel_w1  = (const float*)d_in[33];
  const float* rel_b1  = (const float*)d_in[34];
  const float* rel_w2  = (const float*)d_in[35];
  const float* rel_b2  = (const float*)d_in[36];
  const float* sp_w1   = (const float*)d_in[37];
  const float* sp_b1   = (const float*)d_in[38];
  const float* sp_w2   = (const float*)d_in[39];
  const float* sp_b2   = (const float*)d_in[40];

  float* out = (float*)d_out;
  float* o_boxes  = out + O_BOXES;
  float* o_ent    = out + O_ENT;
  float* o_regc   = out + O_REGC;
  float* o_pos    = out + O_POS;
  float* o_rel    = out + O_REL;
  float* o_scores = out + O_SCORES;
  float* o_cls    = out + O_CLS;
  float* o_reg    = out + O_REG;
  float* o_ctr    = out + O_CTR;

  float* ws = (float*)d_ws;
  // layout (bytes): r1h 0..16.8M, r1l ..33.6M, r2 ..67.1M, Wt ..78.9M, Hbuf/sph/spbuf/pix ..83.8M
  u16*   r1h  = (u16*)ws;
  u16*   r1l  = r1h + 8388608;
  float* r2   = ws + 8388608;
  u16*   roiB = (u16*)r2;                 // alias: r2 dead after rpn_head
  u16*   WtH1 = (u16*)(ws + 16777216);
  u16*   WtL1 = WtH1 + 2359296;
  u16*   WtH2 = WtL1 + 2359296;
  u16*   WtL2 = WtH2 + 589824;
  float* Hbuf = ws + 19726336;
  float* relh = ws + 16777216;            // alias over Wt region (dead before rel_gemm)
  float* sph  = Hbuf + 409600;
  float* spbuf = sph + 204800;
  int*   pixb = (int*)(spbuf + 614400);
  int*   idxb = pixb + 640;

  wt_transform_k<<<(9 * 256 * 1024 + 255) / 256, 256, 0, stream>>>(conv1_w, 1024, WtH1, WtL1);
  wt_transform_k<<<(9 * 256 * 256 + 255) / 256, 256, 0, stream>>>(conv2_w, 256, WtH2, WtL2);
  conv_mfma_k<0><<<dim3(2, 256), 256, 0, stream>>>(
      vf, nullptr, nullptr, WtH1, WtL1, conv1_b, bn1_g, bn1_b, bn1_m, bn1_v, r1h, r1l, nullptr);
  conv_mfma_k<1><<<dim3(2, 256), 256, 0, stream>>>(
      nullptr, r1h, r1l, WtH2, WtL2, conv2_b, bn2_g, bn2_b, bn2_m, bn2_v, nullptr, nullptr, r2);
  rpn_head<<<512, 256, 0, stream>>>(
      r2, cls_w, cls_b, reg_w, reg_b, ctr_w, ctr_b, o_cls, o_reg, o_ctr);
  topk_boxes_k<<<8, 256, 0, stream>>>(o_ctr, o_reg, o_boxes, o_scores, idxb, pixb);
  roi_pool_k<<<160, 256, 0, stream>>>(vf, pixb, roiB);
  zero_k<<<1600, 256, 0, stream>>>(Hbuf, 160 * 2560);
  mlp1_mfma_k<<<dim3(40, 16), 256, 0, stream>>>(roiB, ent_w1, regc_w1, pos_w1, objp_w, Hbuf);
  mlp1_epilogue_k<<<1600, 256, 0, stream>>>(Hbuf, ent_b1, regc_b1, pos_b1, objp_b);
  head2_k<<<(160 * 237 + 255) / 256, 256, 0, stream>>>(
      Hbuf, 2560, 0, ent_w2, ent_b2, 768, 237, 160, o_ent);
  head2_k<<<(160 * 310 + 255) / 256, 256, 0, stream>>>(
      Hbuf, 2560, 768, regc_w2, regc_b2, 768, 310, 160, o_regc);
  head2_k<<<(160 * 2 + 255) / 256, 256, 0, stream>>>(
      Hbuf, 2560, 1536, pos_w2, pos_b2, 256, 2, 160, o_pos);
  sp_hidden_k<<<800, 256, 0, stream>>>(o_boxes, sp_w1, sp_b1, sph);
  sp_out_k<<<2400, 256, 0, stream>>>(sph, sp_w2, sp_b2, spbuf);
  rel_gemm_k<<<dim3(6, 100), 256, 0, stream>>>(Hbuf, spbuf, rel_w1, rel_b1, relh);
  head2_k<<<(3200 * 10 + 255) / 256, 256, 0, stream>>>(
      relh, 768, 0, rel_w2, rel_b2, 768, 10, 3200, o_rel);
}